// Round 20
// baseline (250.646 us; speedup 1.0000x reference)
//
#include <hip/hip_runtime.h>
#include <hip/hip_cooperative_groups.h>

namespace cg = cooperative_groups;

#define NN 100000
#define NE 1600000

constexpr int F_IN = 58;
constexpr int FH2  = 32;
constexpr int KS   = 2;

constexpr int NB   = 391;           // buckets: col >> 8
constexpr int NBLK = 256;           // partition blocks
constexpr int EPB  = NE / NBLK;     // 6250
constexpr int SCANN = NB * NBLK;    // 100096
constexpr int SCAN_BLOCKS = (SCANN + 1023) / 1024;  // 98
constexpr int DN_NODES = 64;
constexpr int DENSE_BLOCKS = (NN + DN_NODES - 1) / DN_NODES;  // 1563
constexpr int LROW = 136;           // padded LDS row stride in shorts

using short8 = __attribute__((ext_vector_type(8))) short;
using f32x4  = __attribute__((ext_vector_type(4))) float;

__device__ inline void splitbf(float v, short& hi, short& lo) {
    unsigned ub = __float_as_uint(v);
    unsigned short h = (unsigned short)(ub >> 16);
    float hif = __uint_as_float(((unsigned)h) << 16);
    float lof = v - hif;
    unsigned short l = (unsigned short)(__float_as_uint(lof) >> 16);
    hi = (short)h; lo = (short)l;
}

__device__ inline unsigned short bf16rne(float v) {
    unsigned u = __float_as_uint(v);
    unsigned r = u + 0x7FFF + ((u >> 16) & 1);
    return (unsigned short)(r >> 16);
}

__device__ inline float bf2f(unsigned short s) {
    return __uint_as_float(((unsigned)s) << 16);
}

// blocks [0,NBLK): per-block bucket histogram (single-copy LDS atomics, int2 loads).
// blocks [NBLK,...): dense layer-1 via split-bf16 MFMA, padded LDS; weights
// split in-block (L2-warm after first block) -- prep_w launch eliminated.
__global__ void k_hist_dense1(const int* __restrict__ col, int* __restrict__ bh,
                              const float* __restrict__ x,
                              const float* __restrict__ Wi, const float* __restrict__ Wr,
                              const float* __restrict__ b,
                              unsigned short* __restrict__ h1b,
                              unsigned short* __restrict__ r1b) {
    __shared__ int hist[NB];
    __shared__ short sA[64 * LROW];
    __shared__ short sB[64 * LROW];
    int tid = threadIdx.x;

    if (blockIdx.x < NBLK) {
        int blk = blockIdx.x;
        for (int i = tid; i < NB; i += 256) hist[i] = 0;
        __syncthreads();
        const int2* c2p = (const int2*)&col[blk * EPB];
        for (int c = tid; c < EPB / 2; c += 256) {
            int2 cc = c2p[c];
            atomicAdd(&hist[cc.x >> 8], 1);
            atomicAdd(&hist[cc.y >> 8], 1);
        }
        __syncthreads();
        for (int i = tid; i < NB; i += 256)
            bh[i * NBLK + blk] = hist[i];
        return;
    }

    int nodeBase = (blockIdx.x - NBLK) * DN_NODES;
    // stage B: split weights f32 -> bf16 hi|lo in-block
    for (int t = tid; t < 1024; t += 256) {
        int c = t >> 4, q4 = t & 15;
        int i0 = q4 * 4;
        int ko = c & 31, kst = ko >> 4, o = ko & 15;
        const float* W = (c < 32) ? Wi : Wr;
        float v0 = 0.f, v1 = 0.f, v2 = 0.f, v3 = 0.f;
        if (i0 + 0 < F_IN) v0 = W[(kst * F_IN + i0 + 0) * 16 + o];
        if (i0 + 1 < F_IN) v1 = W[(kst * F_IN + i0 + 1) * 16 + o];
        if (i0 + 2 < F_IN) v2 = W[(kst * F_IN + i0 + 2) * 16 + o];
        if (i0 + 3 < F_IN) v3 = W[(kst * F_IN + i0 + 3) * 16 + o];
        short h0, l0, h1s, l1s, h2s, l2s, h3s, l3s;
        splitbf(v0, h0, l0); splitbf(v1, h1s, l1s);
        splitbf(v2, h2s, l2s); splitbf(v3, h3s, l3s);
        *(short4*)&sB[c * LROW + q4 * 4]      = make_short4(h0, h1s, h2s, h3s);
        *(short4*)&sB[c * LROW + 64 + q4 * 4] = make_short4(l0, l1s, l2s, l3s);
    }
    // stage A: x rows -> bf16 hi/lo
    for (int t = tid; t < 1024; t += 256) {
        int r = t >> 4, q4 = t & 15;
        int n = nodeBase + r;
        float v0 = 0.f, v1 = 0.f, v2 = 0.f, v3 = 0.f;
        int i0 = q4 * 4;
        if (n < NN && i0 < F_IN) {
            float2 a = *(const float2*)&x[(size_t)n * F_IN + i0];
            v0 = a.x; v1 = a.y;
            if (i0 + 2 < F_IN) {
                float2 c2 = *(const float2*)&x[(size_t)n * F_IN + i0 + 2];
                v2 = c2.x; v3 = c2.y;
            }
        }
        short h0, l0, h1s, l1s, h2s, l2s, h3s, l3s;
        splitbf(v0, h0, l0); splitbf(v1, h1s, l1s);
        splitbf(v2, h2s, l2s); splitbf(v3, h3s, l3s);
        *(short4*)&sA[r * LROW + q4 * 4]      = make_short4(h0, h1s, h2s, h3s);
        *(short4*)&sA[r * LROW + 64 + q4 * 4] = make_short4(l0, l1s, l2s, l3s);
    }
    __syncthreads();

    int lane = tid & 63, w = tid >> 6;
    int r15 = lane & 15, h4 = lane >> 4;
    const short* aB = &sA[(w * 16 + r15) * LROW];
    f32x4 acc0 = {0,0,0,0}, acc1 = {0,0,0,0}, acc2 = {0,0,0,0}, acc3 = {0,0,0,0};
    const int kaA[6] = {0, 32, 0, 32, 64, 96};
    const int kaB[6] = {0, 32, 64, 96, 0, 32};
#pragma unroll
    for (int s = 0; s < 6; s++) {
        short8 af = *(const short8*)&aB[kaA[s] + h4 * 8];
#define BMM(nt, accv) { \
        short8 bf = *(const short8*)&sB[(nt * 16 + r15) * LROW + kaB[s] + h4 * 8]; \
        accv = __builtin_amdgcn_mfma_f32_16x16x32_bf16(af, bf, accv, 0, 0, 0); }
        BMM(0, acc0) BMM(1, acc1) BMM(2, acc2) BMM(3, acc3)
#undef BMM
    }
    int nb0 = nodeBase + w * 16 + h4 * 4;
#define WH(nt, accv) { int colg = nt * 16 + r15; \
    if (nb0 + 0 < NN) h1b[(size_t)(nb0 + 0) * 32 + colg] = bf16rne(accv[0]); \
    if (nb0 + 1 < NN) h1b[(size_t)(nb0 + 1) * 32 + colg] = bf16rne(accv[1]); \
    if (nb0 + 2 < NN) h1b[(size_t)(nb0 + 2) * 32 + colg] = bf16rne(accv[2]); \
    if (nb0 + 3 < NN) h1b[(size_t)(nb0 + 3) * 32 + colg] = bf16rne(accv[3]); }
#define WR(nt, accv) { int colg = nt * 16 + r15 - 32; float bv = b[colg]; \
    if (nb0 + 0 < NN) r1b[(size_t)(nb0 + 0) * 32 + colg] = bf16rne(accv[0] + bv); \
    if (nb0 + 1 < NN) r1b[(size_t)(nb0 + 1) * 32 + colg] = bf16rne(accv[1] + bv); \
    if (nb0 + 2 < NN) r1b[(size_t)(nb0 + 2) * 32 + colg] = bf16rne(accv[2] + bv); \
    if (nb0 + 3 < NN) r1b[(size_t)(nb0 + 3) * 32 + colg] = bf16rne(accv[3] + bv); }
    WH(0, acc0) WH(1, acc1) WR(2, acc2) WR(3, acc3)
#undef WH
#undef WR
}

// Cooperative CSR build: scan1 | scan2 | bscatter | bcsr in ONE kernel,
// grid.sync() between phases (replaces 4 launches).
__global__ void __launch_bounds__(256) k_csr(int* __restrict__ bh,
                                             int* __restrict__ bsum,
                                             int* __restrict__ boff,
                                             const int* __restrict__ row,
                                             const int* __restrict__ col,
                                             int* __restrict__ ebuck,
                                             int* __restrict__ inc,
                                             float* __restrict__ dis,
                                             int* __restrict__ esrc) {
    cg::grid_group grid = cg::this_grid();
    __shared__ int sh[1026];
    int tid = threadIdx.x, b = blockIdx.x;

    // -- Phase A: per-block inclusive scan of bh (98 active blocks) --
    if (b < SCAN_BLOCKS) {
        int* ts = sh;
        int base = b * 1024 + tid * 4;
        int v0 = (base + 0 < SCANN) ? bh[base + 0] : 0;
        int v1 = (base + 1 < SCANN) ? bh[base + 1] : 0;
        int v2 = (base + 2 < SCANN) ? bh[base + 2] : 0;
        int v3 = (base + 3 < SCANN) ? bh[base + 3] : 0;
        int p0 = v0, p1 = p0 + v1, p2 = p1 + v2, p3 = p2 + v3;
        ts[tid] = p3;
        __syncthreads();
        for (int off = 1; off < 256; off <<= 1) {
            int v = (tid >= off) ? ts[tid - off] : 0;
            __syncthreads();
            ts[tid] += v;
            __syncthreads();
        }
        int prev = (tid > 0) ? ts[tid - 1] : 0;
        if (base + 0 < SCANN) bh[base + 0] = prev + p0;
        if (base + 1 < SCANN) bh[base + 1] = prev + p1;
        if (base + 2 < SCANN) bh[base + 2] = prev + p2;
        if (base + 3 < SCANN) bh[base + 3] = prev + p3;
        if (tid == 255) bsum[b] = ts[255];
    }
    grid.sync();

    // -- Phase B: scan of block sums (block 0) --
    if (b == 0) {
        int* s = sh;
        s[tid] = (tid < SCAN_BLOCKS) ? bsum[tid] : 0;
        __syncthreads();
        for (int off = 1; off < 256; off <<= 1) {
            int v = (tid >= off) ? s[tid - off] : 0;
            __syncthreads();
            s[tid] += v;
            __syncthreads();
        }
        if (tid < SCAN_BLOCKS) boff[tid] = (tid > 0) ? s[tid - 1] : 0;
    }
    grid.sync();

    // -- Phase C: bucket-major scatter (256 active blocks) --
    if (b < NBLK) {
        int* cur = sh;
        for (int i = tid; i < NB; i += 256) {
            int idx = i * NBLK + b;
            cur[i] = (idx == 0) ? 0 : bh[idx - 1] + boff[(idx - 1) >> 10];
        }
        __syncthreads();
        int base = b * EPB;
        const int2* c2p = (const int2*)&col[base];
        const int2* r2p = (const int2*)&row[base];
        for (int c = tid; c < EPB / 2; c += 256) {
            int2 cc = c2p[c];
            int2 rr = r2p[c];
            int p0 = atomicAdd(&cur[cc.x >> 8], 1);
            ebuck[p0] = (rr.x << 8) | (cc.x & 255);
            int p1 = atomicAdd(&cur[cc.y >> 8], 1);
            ebuck[p1] = (rr.y << 8) | (cc.y & 255);
        }
    }
    grid.sync();

    // -- Phase D: per-bucket CSR finalize (all 391 blocks) --
    {
        int* cnt = sh;          // 514
        int* scn = sh + 514;    // 256
        int* cur = sh + 770;    // 256
        int i0 = b * NBLK - 1, i1 = (b + 1) * NBLK - 1;
        int start = (b == 0) ? 0 : bh[i0] + boff[i0 >> 10];
        int end   = bh[i1] + boff[i1 >> 10];
        cnt[tid] = 0; cnt[257 + tid] = 0;
        if (tid < 2) cnt[256 + tid * 257] = 0;
        __syncthreads();
        int c0 = (tid & 1) * 257;
        for (int j = start + tid; j < end; j += 256)
            atomicAdd(&cnt[c0 + (ebuck[j] & 255)], 1);
        __syncthreads();
        int v = cnt[tid] + cnt[257 + tid];
        scn[tid] = v;
        __syncthreads();
        for (int off = 1; off < 256; off <<= 1) {
            int t = (tid >= off) ? scn[tid - off] : 0;
            __syncthreads();
            scn[tid] += t;
            __syncthreads();
        }
        int incl = scn[tid];
        cur[tid] = start + incl - v;
        int colIdx = (b << 8) + tid;
        if (colIdx < NN) {
            inc[colIdx] = start + incl;
            dis[colIdx] = (v > 0) ? rsqrtf((float)v) : 0.f;
        }
        __syncthreads();
        for (int j = start + tid; j < end; j += 256) {
            int e = ebuck[j];
            int pos = atomicAdd(&cur[e & 255], 1);
            esrc[pos] = e >> 8;
        }
    }
}

// layer1 gather + relu + K-mean + dense2. 8 lanes/node, bf16 h1 short4 rows,
// 4 edges per int4, w = dis[s]*dis[n] on the fly.
__global__ void k_gather1_mid(const int* __restrict__ inc, const int* __restrict__ esrc,
                              const float* __restrict__ dis,
                              const unsigned short* __restrict__ h1b,
                              const unsigned short* __restrict__ r1b,
                              const float4* __restrict__ Wi2, const float4* __restrict__ Wr2,
                              const float* __restrict__ b2,
                              float* __restrict__ h2, float* __restrict__ r2) {
    int tid = blockIdx.x * blockDim.x + threadIdx.x;
    int n = tid >> 3, l = tid & 7;
    if (n >= NN) return;
    int js = (n == 0) ? 0 : inc[n - 1];
    int je = inc[n];
    float dn = dis[n];
    short4 rv4 = *(const short4*)&r1b[(size_t)n * 32 + l * 4];
    float4 acc;
    acc.x = bf2f((unsigned short)rv4.x);
    acc.y = bf2f((unsigned short)rv4.y);
    acc.z = bf2f((unsigned short)rv4.z);
    acc.w = bf2f((unsigned short)rv4.w);
    int j = js;
#define EDGE1(ss) { \
        float w = dis[ss] * dn; \
        short4 hv = *(const short4*)&h1b[(size_t)(ss) * 32 + l * 4]; \
        acc.x = fmaf(w, bf2f((unsigned short)hv.x), acc.x); \
        acc.y = fmaf(w, bf2f((unsigned short)hv.y), acc.y); \
        acc.z = fmaf(w, bf2f((unsigned short)hv.z), acc.z); \
        acc.w = fmaf(w, bf2f((unsigned short)hv.w), acc.w); }
    while (j < je && (j & 3)) { EDGE1(esrc[j]) j++; }
    for (; j + 3 < je; j += 4) {
        int4 s4 = *(const int4*)&esrc[j];
        EDGE1(s4.x) EDGE1(s4.y) EDGE1(s4.z) EDGE1(s4.w)
    }
    for (; j < je; j++) { EDGE1(esrc[j]) }
#undef EDGE1
    acc.x = fmaxf(acc.x, 0.f); acc.y = fmaxf(acc.y, 0.f);
    acc.z = fmaxf(acc.z, 0.f); acc.w = fmaxf(acc.w, 0.f);
    float4 h;
    h.x = 0.5f * (acc.x + __shfl_xor(acc.x, 4));
    h.y = 0.5f * (acc.y + __shfl_xor(acc.y, 4));
    h.z = 0.5f * (acc.z + __shfl_xor(acc.z, 4));
    h.w = 0.5f * (acc.w + __shfl_xor(acc.w, 4));
    float4 wi = Wi2[l], wr = Wr2[l];
    float p1 = h.x * wi.x + h.y * wi.y + h.z * wi.z + h.w * wi.w;
    float p2 = h.x * wr.x + h.y * wr.y + h.z * wr.z + h.w * wr.w;
    p1 += __shfl_xor(p1, 1); p1 += __shfl_xor(p1, 2);
    p2 += __shfl_xor(p2, 1); p2 += __shfl_xor(p2, 2);
    if ((l & 3) == 0) {
        int k = l >> 2;
        h2[n * 2 + k] = p1;
        r2[n * 2 + k] = p2 + b2[k];
    }
}

// layer2 gather: 8 lanes/node, edge-parallel, src-only payload
__global__ void k_gather2(const int* __restrict__ inc, const int* __restrict__ esrc,
                          const float* __restrict__ dis,
                          const float* __restrict__ h2, const float* __restrict__ r2,
                          float* __restrict__ out) {
    int tid = blockIdx.x * blockDim.x + threadIdx.x;
    int n = tid >> 3, l = tid & 7;
    if (n >= NN) return;
    int js = (n == 0) ? 0 : inc[n - 1];
    int je = inc[n];
    float dn = dis[n];
    float a0 = 0.f, a1v = 0.f;
    for (int j = js + l; j < je; j += 8) {
        int s = esrc[j];
        float w = dis[s] * dn;
        float2 hv = *(const float2*)&h2[(size_t)s * 2];
        a0  = fmaf(w, hv.x, a0);
        a1v = fmaf(w, hv.y, a1v);
    }
    a0  += __shfl_xor(a0, 1);  a0  += __shfl_xor(a0, 2);  a0  += __shfl_xor(a0, 4);
    a1v += __shfl_xor(a1v, 1); a1v += __shfl_xor(a1v, 2); a1v += __shfl_xor(a1v, 4);
    if (l == 0) {
        float2 rv = *(const float2*)&r2[(size_t)n * 2];
        out[n] = 0.5f * (fmaxf(a0 + rv.x, 0.f) + fmaxf(a1v + rv.y, 0.f));
    }
}

extern "C" void kernel_launch(void* const* d_in, const int* in_sizes, int n_in,
                              void* d_out, int out_size, void* d_ws, size_t ws_size,
                              hipStream_t stream) {
    const float* x   = (const float*)d_in[0];
    const int*   ei  = (const int*)d_in[1];
    const float* Wi1 = (const float*)d_in[2];
    const float* Wr1 = (const float*)d_in[3];
    const float* b1  = (const float*)d_in[4];
    const float* Wi2 = (const float*)d_in[5];
    const float* Wr2 = (const float*)d_in[6];
    const float* b2  = (const float*)d_in[7];
    float* out = (float*)d_out;

    const int* row = ei;
    const int* col = ei + NE;

    int*   bh    = (int*)d_ws;                       // 100096
    int*   bsum  = bh + SCANN;                       // 128
    int*   boff  = bsum + 128;                       // 128
    float* dis   = (float*)(boff + 128);             // NN
    int*   inc   = (int*)(dis + NN);                 // NN
    int*   ebuck = inc + NN;                         // NE
    int*   esrc  = ebuck + NE;                       // NE
    unsigned short* h1b = (unsigned short*)(esrc + NE);   // NN*32 bf16
    unsigned short* r1b = h1b + (size_t)NN * FH2;         // NN*32 bf16
    float* h2    = (float*)(r1b + (size_t)NN * FH2); // NN*2
    float* r2    = h2 + (size_t)NN * KS;             // NN*2

    const int B = 256;
    k_hist_dense1<<<NBLK + DENSE_BLOCKS, B, 0, stream>>>(col, bh, x, Wi1, Wr1, b1, h1b, r1b);
    {
        void* args[] = {(void*)&bh, (void*)&bsum, (void*)&boff, (void*)&row,
                        (void*)&col, (void*)&ebuck, (void*)&inc, (void*)&dis,
                        (void*)&esrc};
        hipLaunchCooperativeKernel((void*)k_csr, dim3(NB), dim3(B), args, 0, stream);
    }
    k_gather1_mid<<<(NN * 8 + B - 1) / B, B, 0, stream>>>(inc, esrc, dis, h1b, r1b,
        (const float4*)Wi2, (const float4*)Wr2, b2, h2, r2);
    k_gather2<<<(NN * 8 + B - 1) / B, B, 0, stream>>>(inc, esrc, dis, h2, r2, out);
}

// Round 21
// 101.570 us; speedup vs baseline: 2.4677x; 2.4677x over previous
//
#include <hip/hip_runtime.h>

#define NN 100000
#define NE 1600000

constexpr int F_IN = 58;
constexpr int FH2  = 32;
constexpr int KS   = 2;

constexpr int NB   = 391;           // buckets: col >> 8
constexpr int NBLK = 256;           // partition blocks
constexpr int EPB  = NE / NBLK;     // 6250
constexpr int SCANN = NB * NBLK;    // 100096
constexpr int SCAN_BLOCKS = (SCANN + 1023) / 1024;  // 98
constexpr int DN_NODES = 64;
constexpr int DENSE_BLOCKS = (NN + DN_NODES - 1) / DN_NODES;  // 1563
constexpr int LROW = 136;           // padded LDS row stride in shorts
constexpr int WELEM = KS * F_IN * 16;  // 1856 floats per weight tensor

using short8 = __attribute__((ext_vector_type(8))) short;
using f32x4  = __attribute__((ext_vector_type(4))) float;

__device__ inline void splitbf(float v, short& hi, short& lo) {
    unsigned ub = __float_as_uint(v);
    unsigned short h = (unsigned short)(ub >> 16);
    float hif = __uint_as_float(((unsigned)h) << 16);
    float lof = v - hif;
    unsigned short l = (unsigned short)(__float_as_uint(lof) >> 16);
    hi = (short)h; lo = (short)l;
}

__device__ inline unsigned short bf16rne(float v) {
    unsigned u = __float_as_uint(v);
    unsigned r = u + 0x7FFF + ((u >> 16) & 1);
    return (unsigned short)(r >> 16);
}

__device__ inline float bf2f(unsigned short s) {
    return __uint_as_float(((unsigned)s) << 16);
}

// blocks [0,NBLK): per-block bucket histogram (single-copy LDS atomics, int2 loads).
// blocks [NBLK,...): dense layer-1 via split-bf16 MFMA, padded LDS.
// Weights split in-block with COALESCED linear reads (prep_w launch eliminated).
__global__ void k_hist_dense1(const int* __restrict__ col, int* __restrict__ bh,
                              const float* __restrict__ x,
                              const float* __restrict__ Wi, const float* __restrict__ Wr,
                              const float* __restrict__ b,
                              unsigned short* __restrict__ h1b,
                              unsigned short* __restrict__ r1b) {
    __shared__ int hist[NB];
    __shared__ short sA[64 * LROW];
    __shared__ short sB[64 * LROW];
    int tid = threadIdx.x;

    if (blockIdx.x < NBLK) {
        int blk = blockIdx.x;
        for (int i = tid; i < NB; i += 256) hist[i] = 0;
        __syncthreads();
        const int2* c2p = (const int2*)&col[blk * EPB];
        for (int c = tid; c < EPB / 2; c += 256) {
            int2 cc = c2p[c];
            atomicAdd(&hist[cc.x >> 8], 1);
            atomicAdd(&hist[cc.y >> 8], 1);
        }
        __syncthreads();
        for (int i = tid; i < NB; i += 256)
            bh[i * NBLK + blk] = hist[i];
        return;
    }

    int nodeBase = (blockIdx.x - NBLK) * DN_NODES;
    // stage B: coalesced weight read + split. W layout [kst][i][o] flat.
    for (int idx = tid; idx < WELEM; idx += 256) {
        int kst = (idx >= F_IN * 16) ? 1 : 0;
        int rem = idx - kst * (F_IN * 16);
        int i = rem >> 4, o = rem & 15;
        int c = kst * 16 + o;                 // Wi col 0..31
        short hi, lo;
        splitbf(Wi[idx], hi, lo);
        sB[c * LROW + i] = hi;
        sB[c * LROW + 64 + i] = lo;
        splitbf(Wr[idx], hi, lo);
        sB[(c + 32) * LROW + i] = hi;         // Wr col 32..63
        sB[(c + 32) * LROW + 64 + i] = lo;
    }
    for (int t = tid; t < 64 * 6; t += 256) { // zero-pad i = 58..63
        int c = t / 6, i = 58 + (t - (t / 6) * 6);
        sB[c * LROW + i] = 0;
        sB[c * LROW + 64 + i] = 0;
    }
    // stage A: x rows -> bf16 hi/lo
    for (int t = tid; t < 1024; t += 256) {
        int r = t >> 4, q4 = t & 15;
        int n = nodeBase + r;
        float v0 = 0.f, v1 = 0.f, v2 = 0.f, v3 = 0.f;
        int i0 = q4 * 4;
        if (n < NN && i0 < F_IN) {
            float2 a = *(const float2*)&x[(size_t)n * F_IN + i0];
            v0 = a.x; v1 = a.y;
            if (i0 + 2 < F_IN) {
                float2 c2 = *(const float2*)&x[(size_t)n * F_IN + i0 + 2];
                v2 = c2.x; v3 = c2.y;
            }
        }
        short h0, l0, h1s, l1s, h2s, l2s, h3s, l3s;
        splitbf(v0, h0, l0); splitbf(v1, h1s, l1s);
        splitbf(v2, h2s, l2s); splitbf(v3, h3s, l3s);
        *(short4*)&sA[r * LROW + q4 * 4]      = make_short4(h0, h1s, h2s, h3s);
        *(short4*)&sA[r * LROW + 64 + q4 * 4] = make_short4(l0, l1s, l2s, l3s);
    }
    __syncthreads();

    int lane = tid & 63, w = tid >> 6;
    int r15 = lane & 15, h4 = lane >> 4;
    const short* aB = &sA[(w * 16 + r15) * LROW];
    f32x4 acc0 = {0,0,0,0}, acc1 = {0,0,0,0}, acc2 = {0,0,0,0}, acc3 = {0,0,0,0};
    const int kaA[6] = {0, 32, 0, 32, 64, 96};
    const int kaB[6] = {0, 32, 64, 96, 0, 32};
#pragma unroll
    for (int s = 0; s < 6; s++) {
        short8 af = *(const short8*)&aB[kaA[s] + h4 * 8];
#define BMM(nt, accv) { \
        short8 bf = *(const short8*)&sB[(nt * 16 + r15) * LROW + kaB[s] + h4 * 8]; \
        accv = __builtin_amdgcn_mfma_f32_16x16x32_bf16(af, bf, accv, 0, 0, 0); }
        BMM(0, acc0) BMM(1, acc1) BMM(2, acc2) BMM(3, acc3)
#undef BMM
    }
    int nb0 = nodeBase + w * 16 + h4 * 4;
#define WH(nt, accv) { int colg = nt * 16 + r15; \
    if (nb0 + 0 < NN) h1b[(size_t)(nb0 + 0) * 32 + colg] = bf16rne(accv[0]); \
    if (nb0 + 1 < NN) h1b[(size_t)(nb0 + 1) * 32 + colg] = bf16rne(accv[1]); \
    if (nb0 + 2 < NN) h1b[(size_t)(nb0 + 2) * 32 + colg] = bf16rne(accv[2]); \
    if (nb0 + 3 < NN) h1b[(size_t)(nb0 + 3) * 32 + colg] = bf16rne(accv[3]); }
#define WR(nt, accv) { int colg = nt * 16 + r15 - 32; float bv = b[colg]; \
    if (nb0 + 0 < NN) r1b[(size_t)(nb0 + 0) * 32 + colg] = bf16rne(accv[0] + bv); \
    if (nb0 + 1 < NN) r1b[(size_t)(nb0 + 1) * 32 + colg] = bf16rne(accv[1] + bv); \
    if (nb0 + 2 < NN) r1b[(size_t)(nb0 + 2) * 32 + colg] = bf16rne(accv[2] + bv); \
    if (nb0 + 3 < NN) r1b[(size_t)(nb0 + 3) * 32 + colg] = bf16rne(accv[3] + bv); }
    WH(0, acc0) WH(1, acc1) WR(2, acc2) WR(3, acc3)
#undef WH
#undef WR
}

__global__ void k_scan1(int* __restrict__ bh, int* __restrict__ bsum) {
    __shared__ int ts[256];
    int tid = threadIdx.x;
    int base = blockIdx.x * 1024 + tid * 4;
    int v0 = (base + 0 < SCANN) ? bh[base + 0] : 0;
    int v1 = (base + 1 < SCANN) ? bh[base + 1] : 0;
    int v2 = (base + 2 < SCANN) ? bh[base + 2] : 0;
    int v3 = (base + 3 < SCANN) ? bh[base + 3] : 0;
    int p0 = v0, p1 = p0 + v1, p2 = p1 + v2, p3 = p2 + v3;
    ts[tid] = p3;
    __syncthreads();
    for (int off = 1; off < 256; off <<= 1) {
        int v = (tid >= off) ? ts[tid - off] : 0;
        __syncthreads();
        ts[tid] += v;
        __syncthreads();
    }
    int prev = (tid > 0) ? ts[tid - 1] : 0;
    if (base + 0 < SCANN) bh[base + 0] = prev + p0;
    if (base + 1 < SCANN) bh[base + 1] = prev + p1;
    if (base + 2 < SCANN) bh[base + 2] = prev + p2;
    if (base + 3 < SCANN) bh[base + 3] = prev + p3;
    if (tid == 255) bsum[blockIdx.x] = ts[255];
}

// in-LDS exclusive scan of bsum (98 entries) -> sb[]; boff(q) = (q>0)? sb[q-1]:0
#define INLINE_BOFF(sb) \
    if (tid < 128) sb[tid] = (tid < SCAN_BLOCKS) ? bsum[tid] : 0; \
    __syncthreads(); \
    for (int off = 1; off < 128; off <<= 1) { \
        int t_ = (tid < 128 && tid >= off) ? sb[tid - off] : 0; \
        __syncthreads(); \
        if (tid < 128) sb[tid] += t_; \
        __syncthreads(); \
    }
#define BOFF(sb, q) (((q) > 0) ? sb[(q) - 1] : 0)

// scatter to bucket-major; boff computed inline (scan2 launch eliminated)
__global__ void k_bscatter(const int* __restrict__ row, const int* __restrict__ col,
                           const int* __restrict__ bh, const int* __restrict__ bsum,
                           int* __restrict__ ebuck) {
    __shared__ int cur[NB];
    __shared__ int sb[128];
    int tid = threadIdx.x, blk = blockIdx.x;
    INLINE_BOFF(sb)
    for (int i = tid; i < NB; i += 256) {
        int idx = i * NBLK + blk;
        cur[i] = (idx == 0) ? 0 : bh[idx - 1] + BOFF(sb, (idx - 1) >> 10);
    }
    __syncthreads();
    int base = blk * EPB;
    const int2* c2p = (const int2*)&col[base];
    const int2* r2p = (const int2*)&row[base];
    for (int c = tid; c < EPB / 2; c += 256) {
        int2 cc = c2p[c];
        int2 rr = r2p[c];
        int p0 = atomicAdd(&cur[cc.x >> 8], 1);
        ebuck[p0] = (rr.x << 8) | (cc.x & 255);
        int p1 = atomicAdd(&cur[cc.y >> 8], 1);
        ebuck[p1] = (rr.y << 8) | (cc.y & 255);
    }
}

// MERGED per-bucket CSR build; boff inline
__global__ void __launch_bounds__(256) k_bcsr(const int* __restrict__ bh,
                                              const int* __restrict__ bsum,
                                              const int* __restrict__ ebuck,
                                              int* __restrict__ inc, float* __restrict__ dis,
                                              int* __restrict__ esrc) {
    __shared__ int cnt[514];
    __shared__ int scn[256];
    __shared__ int cur[256];
    __shared__ int sb[128];
    int b = blockIdx.x, tid = threadIdx.x;
    INLINE_BOFF(sb)
    int i0 = b * NBLK - 1, i1 = (b + 1) * NBLK - 1;
    int start = (b == 0) ? 0 : bh[i0] + BOFF(sb, i0 >> 10);
    int end   = bh[i1] + BOFF(sb, i1 >> 10);
    cnt[tid] = 0; cnt[257 + tid] = 0;
    __syncthreads();
    int c0 = (tid & 1) * 257;
    for (int j = start + tid; j < end; j += 256)
        atomicAdd(&cnt[c0 + (ebuck[j] & 255)], 1);
    __syncthreads();
    int v = cnt[tid] + cnt[257 + tid];
    scn[tid] = v;
    __syncthreads();
    for (int off = 1; off < 256; off <<= 1) {
        int t = (tid >= off) ? scn[tid - off] : 0;
        __syncthreads();
        scn[tid] += t;
        __syncthreads();
    }
    int incl = scn[tid];
    cur[tid] = start + incl - v;
    int colIdx = (b << 8) + tid;
    if (colIdx < NN) {
        inc[colIdx] = start + incl;
        dis[colIdx] = (v > 0) ? rsqrtf((float)v) : 0.f;
    }
    __syncthreads();
    for (int j = start + tid; j < end; j += 256) {
        int e = ebuck[j];
        int pos = atomicAdd(&cur[e & 255], 1);
        esrc[pos] = e >> 8;
    }
}

// layer1 gather + relu + K-mean + dense2. 8 lanes/node, bf16 h1 short4 rows,
// 4 edges per int4, w = dis[s]*dis[n] on the fly.
__global__ void k_gather1_mid(const int* __restrict__ inc, const int* __restrict__ esrc,
                              const float* __restrict__ dis,
                              const unsigned short* __restrict__ h1b,
                              const unsigned short* __restrict__ r1b,
                              const float4* __restrict__ Wi2, const float4* __restrict__ Wr2,
                              const float* __restrict__ b2,
                              float* __restrict__ h2, float* __restrict__ r2) {
    int tid = blockIdx.x * blockDim.x + threadIdx.x;
    int n = tid >> 3, l = tid & 7;
    if (n >= NN) return;
    int js = (n == 0) ? 0 : inc[n - 1];
    int je = inc[n];
    float dn = dis[n];
    short4 rv4 = *(const short4*)&r1b[(size_t)n * 32 + l * 4];
    float4 acc;
    acc.x = bf2f((unsigned short)rv4.x);
    acc.y = bf2f((unsigned short)rv4.y);
    acc.z = bf2f((unsigned short)rv4.z);
    acc.w = bf2f((unsigned short)rv4.w);
    int j = js;
#define EDGE1(ss) { \
        float w = dis[ss] * dn; \
        short4 hv = *(const short4*)&h1b[(size_t)(ss) * 32 + l * 4]; \
        acc.x = fmaf(w, bf2f((unsigned short)hv.x), acc.x); \
        acc.y = fmaf(w, bf2f((unsigned short)hv.y), acc.y); \
        acc.z = fmaf(w, bf2f((unsigned short)hv.z), acc.z); \
        acc.w = fmaf(w, bf2f((unsigned short)hv.w), acc.w); }
    while (j < je && (j & 3)) { EDGE1(esrc[j]) j++; }
    for (; j + 3 < je; j += 4) {
        int4 s4 = *(const int4*)&esrc[j];
        EDGE1(s4.x) EDGE1(s4.y) EDGE1(s4.z) EDGE1(s4.w)
    }
    for (; j < je; j++) { EDGE1(esrc[j]) }
#undef EDGE1
    acc.x = fmaxf(acc.x, 0.f); acc.y = fmaxf(acc.y, 0.f);
    acc.z = fmaxf(acc.z, 0.f); acc.w = fmaxf(acc.w, 0.f);
    float4 h;
    h.x = 0.5f * (acc.x + __shfl_xor(acc.x, 4));
    h.y = 0.5f * (acc.y + __shfl_xor(acc.y, 4));
    h.z = 0.5f * (acc.z + __shfl_xor(acc.z, 4));
    h.w = 0.5f * (acc.w + __shfl_xor(acc.w, 4));
    float4 wi = Wi2[l], wr = Wr2[l];
    float p1 = h.x * wi.x + h.y * wi.y + h.z * wi.z + h.w * wi.w;
    float p2 = h.x * wr.x + h.y * wr.y + h.z * wr.z + h.w * wr.w;
    p1 += __shfl_xor(p1, 1); p1 += __shfl_xor(p1, 2);
    p2 += __shfl_xor(p2, 1); p2 += __shfl_xor(p2, 2);
    if ((l & 3) == 0) {
        int k = l >> 2;
        h2[n * 2 + k] = p1;
        r2[n * 2 + k] = p2 + b2[k];
    }
}

// layer2 gather: 8 lanes/node, edge-parallel, src-only payload
__global__ void k_gather2(const int* __restrict__ inc, const int* __restrict__ esrc,
                          const float* __restrict__ dis,
                          const float* __restrict__ h2, const float* __restrict__ r2,
                          float* __restrict__ out) {
    int tid = blockIdx.x * blockDim.x + threadIdx.x;
    int n = tid >> 3, l = tid & 7;
    if (n >= NN) return;
    int js = (n == 0) ? 0 : inc[n - 1];
    int je = inc[n];
    float dn = dis[n];
    float a0 = 0.f, a1v = 0.f;
    for (int j = js + l; j < je; j += 8) {
        int s = esrc[j];
        float w = dis[s] * dn;
        float2 hv = *(const float2*)&h2[(size_t)s * 2];
        a0  = fmaf(w, hv.x, a0);
        a1v = fmaf(w, hv.y, a1v);
    }
    a0  += __shfl_xor(a0, 1);  a0  += __shfl_xor(a0, 2);  a0  += __shfl_xor(a0, 4);
    a1v += __shfl_xor(a1v, 1); a1v += __shfl_xor(a1v, 2); a1v += __shfl_xor(a1v, 4);
    if (l == 0) {
        float2 rv = *(const float2*)&r2[(size_t)n * 2];
        out[n] = 0.5f * (fmaxf(a0 + rv.x, 0.f) + fmaxf(a1v + rv.y, 0.f));
    }
}

extern "C" void kernel_launch(void* const* d_in, const int* in_sizes, int n_in,
                              void* d_out, int out_size, void* d_ws, size_t ws_size,
                              hipStream_t stream) {
    const float* x   = (const float*)d_in[0];
    const int*   ei  = (const int*)d_in[1];
    const float* Wi1 = (const float*)d_in[2];
    const float* Wr1 = (const float*)d_in[3];
    const float* b1  = (const float*)d_in[4];
    const float* Wi2 = (const float*)d_in[5];
    const float* Wr2 = (const float*)d_in[6];
    const float* b2  = (const float*)d_in[7];
    float* out = (float*)d_out;

    const int* row = ei;
    const int* col = ei + NE;

    int*   bh    = (int*)d_ws;                       // 100096
    int*   bsum  = bh + SCANN;                       // 128
    float* dis   = (float*)(bsum + 128);             // NN
    int*   inc   = (int*)(dis + NN);                 // NN
    int*   ebuck = inc + NN;                         // NE
    int*   esrc  = ebuck + NE;                       // NE
    unsigned short* h1b = (unsigned short*)(esrc + NE);   // NN*32 bf16
    unsigned short* r1b = h1b + (size_t)NN * FH2;         // NN*32 bf16
    float* h2    = (float*)(r1b + (size_t)NN * FH2); // NN*2
    float* r2    = h2 + (size_t)NN * KS;             // NN*2

    const int B = 256;
    k_hist_dense1<<<NBLK + DENSE_BLOCKS, B, 0, stream>>>(col, bh, x, Wi1, Wr1, b1, h1b, r1b);
    k_scan1<<<SCAN_BLOCKS, B, 0, stream>>>(bh, bsum);
    k_bscatter<<<NBLK, B, 0, stream>>>(row, col, bh, bsum, ebuck);
    k_bcsr<<<NB, B, 0, stream>>>(bh, bsum, ebuck, inc, dis, esrc);
    k_gather1_mid<<<(NN * 8 + B - 1) / B, B, 0, stream>>>(inc, esrc, dis, h1b, r1b,
        (const float4*)Wi2, (const float4*)Wr2, b2, h2, r2);
    k_gather2<<<(NN * 8 + B - 1) / B, B, 0, stream>>>(inc, esrc, dis, h2, r2, out);
}